// Round 2
// baseline (91.326 us; speedup 1.0000x reference)
//
#include <hip/hip_runtime.h>

// GAPooling: out[b,n,c] = mean_k x[b, idx[b,n,k], c]
// B=16, N=4096, K=32, C=64, fp32. idx int64-or-int32 (runtime-detected).
//
// R14 = FUSED single kernel. Post-mortem of R12/R13 (87.4 vs 88.9, both ~= R10's
// 87.2 despite structurally different gathers) shows the random-row LDS gather
// costs only ~6 us (256 dwords/wave spread ~uniformly over 32 banks -> ~1.2x
// penalty, NOT the N/2.8 law), and the total is dominated by fixed costs:
// poison-fill + prep launch + workspace round-trip. So: delete prep.
//   Each block (b, chunk, q) builds its own 64 KiB bf16 tile straight from x
//   (8 rows/thread, pk_bf16 in-register, ds_write_b128) and reads idx directly
//   (int64: 16B = 2 neighbors, coalesced 256 B/point; L3-resident redundancy).
//   Gather = per-lane ds_read_b128 (R12 style, the cheaper variant).
// No workspace use at all.

#define BB 16
#define NN 4096
#define KK 32
#define CC 64
#define CH8 8
#define NCHUNK (CC / CH8)            // 8
#define NQ 4                         // point quarters
#define PTS (NN / NQ)                // 1024
#define THREADS 512

__device__ __forceinline__ uint pk_bf16(float a, float b) {
    uint ua = __float_as_uint(a);
    ua = (ua + 0x7fffu + ((ua >> 16) & 1u)) >> 16;
    uint ub = __float_as_uint(b);
    ub = (ub + 0x7fffu + ((ub >> 16) & 1u)) & 0xffff0000u;
    return ua | ub;
}

__device__ __forceinline__ void acc8(float a[8], uint4 r) {
    a[0] += __uint_as_float(r.x << 16);
    a[1] += __uint_as_float(r.x & 0xffff0000u);
    a[2] += __uint_as_float(r.y << 16);
    a[3] += __uint_as_float(r.y & 0xffff0000u);
    a[4] += __uint_as_float(r.z << 16);
    a[5] += __uint_as_float(r.z & 0xffff0000u);
    a[6] += __uint_as_float(r.w << 16);
    a[7] += __uint_as_float(r.w & 0xffff0000u);
}

__global__ __launch_bounds__(THREADS, 4)
void gapool_fused(const float* __restrict__ x,
                  const int* __restrict__ idx32,
                  float* __restrict__ out) {
    __shared__ uint4 tile[NN];           // 64 KiB: row n = 8 bf16 channels

    const int bid = blockIdx.x;          // g*16 + b
    const int b = bid & 15;
    const int g = bid >> 4;              // 0..31 = q*8 + chunk
    const int chunk = g & (NCHUNK - 1);
    const int q = g >> 3;
    const int tid = threadIdx.x;
    const float s = 1.0f / KK;

    // idx dtype probe (int64 -> all odd dwords zero; values < 4096).
    int vprobe = idx32[2 * (tid & 63) + 1];
    const bool is64 = (__ballot(vprobe != 0) == 0ULL);

    // Build bf16 tile for (b, chunk): rows 0..4095, channels chunk*8..chunk*8+7.
    // Lane-consecutive rows -> 32 B per lane strided 256 B; L3-served after
    // first touch (x = 16 MiB, read 4x across q-blocks).
    {
        const float4* __restrict__ x4 =
            (const float4*)x + (size_t)b * NN * (CC / 4) + chunk * 2;
#pragma unroll
        for (int i = 0; i < NN / THREADS; ++i) {
            const int r = i * THREADS + tid;
            const float4 v0 = x4[(size_t)r * (CC / 4)];
            const float4 v1 = x4[(size_t)r * (CC / 4) + 1];
            tile[r] = make_uint4(pk_bf16(v0.x, v0.y), pk_bf16(v0.z, v0.w),
                                 pk_bf16(v1.x, v1.y), pk_bf16(v1.z, v1.w));
        }
    }
    __syncthreads();

    const size_t pbase = (size_t)b * NN + (size_t)q * PTS;
    float* __restrict__ outq = out + pbase * CC + chunk * CH8;

    if (is64) {
        // 2 neighbors per uint4 (low dwords hold the value).
        const uint4* __restrict__ ib = (const uint4*)idx32 + pbase * (KK / 2);
#pragma unroll
        for (int pp = 0; pp < PTS / THREADS; ++pp) {
            const int p = pp * THREADS + tid;
            const uint4* __restrict__ ip = ib + (size_t)p * (KK / 2);
            float a[8] = {0.f, 0.f, 0.f, 0.f, 0.f, 0.f, 0.f, 0.f};
#pragma unroll
            for (int t = 0; t < KK / 2; ++t) {
                const uint4 w = ip[t];
                acc8(a, tile[w.x]);
                acc8(a, tile[w.z]);
            }
            float4* op = (float4*)(outq + (size_t)p * CC);
            op[0] = make_float4(a[0] * s, a[1] * s, a[2] * s, a[3] * s);
            op[1] = make_float4(a[4] * s, a[5] * s, a[6] * s, a[7] * s);
        }
    } else {
        // 4 neighbors per uint4.
        const uint4* __restrict__ ib = (const uint4*)idx32 + pbase * (KK / 4);
#pragma unroll
        for (int pp = 0; pp < PTS / THREADS; ++pp) {
            const int p = pp * THREADS + tid;
            const uint4* __restrict__ ip = ib + (size_t)p * (KK / 4);
            float a[8] = {0.f, 0.f, 0.f, 0.f, 0.f, 0.f, 0.f, 0.f};
#pragma unroll
            for (int t = 0; t < KK / 4; ++t) {
                const uint4 w = ip[t];
                acc8(a, tile[w.x]);
                acc8(a, tile[w.y]);
                acc8(a, tile[w.z]);
                acc8(a, tile[w.w]);
            }
            float4* op = (float4*)(outq + (size_t)p * CC);
            op[0] = make_float4(a[0] * s, a[1] * s, a[2] * s, a[3] * s);
            op[1] = make_float4(a[4] * s, a[5] * s, a[6] * s, a[7] * s);
        }
    }
}

extern "C" void kernel_launch(void* const* d_in, const int* in_sizes, int n_in,
                              void* d_out, int out_size, void* d_ws, size_t ws_size,
                              hipStream_t stream) {
    const float* x     = (const float*)d_in[0];
    const int*   idx32 = (const int*)d_in[1];
    float*       out   = (float*)d_out;
    (void)d_ws; (void)ws_size;

    gapool_fused<<<BB * NCHUNK * NQ, THREADS, 0, stream>>>(x, idx32, out);
}

// Round 3
// 86.075 us; speedup vs baseline: 1.0610x; 1.0610x over previous
//
#include <hip/hip_runtime.h>

// GAPooling: out[b,n,c] = mean_k x[b, idx[b,n,k], c]
// B=16, N=4096, K=32, C=64, fp32. idx int64-or-int32 (runtime-detected).
//
// R15 = NO-LDS direct-from-L2 gather.
// Post-mortem R10..R14: dur_us carries a fixed ~44us poison-fill; the kernel
// budget is ~43-47us in every LDS-tile variant regardless of gather style ->
// the tile design itself (2 blocks/CU occupancy, staging barrier, x4 tile
// redundancy, x8 idx redundancy) is the cost. But x per batch is 0.5 MiB in
// bf16 = L2-resident, and a bf16 row is 128 B contiguous = 2 full cachelines,
// so direct gather from L2 wastes nothing.
//   prep: x fp32 -> bf16 row-major [b][n][64] (8 MiB workspace).
//   main: 8 lanes/point, lane owns 8 channels (1 uint4 of the row);
//     preload 4 idx/lane, __shfl(width=8) per neighbor, global dwordx4 gather,
//     unpack+accumulate fp32, coalesced float4 x2 store. No LDS, no barriers,
//     low VGPR -> 8 blocks/CU. Batch->XCD affinity: b = bid & 15.

#define BB 16
#define NN 4096
#define KK 32
#define CC 64
#define THREADS 256
#define MAIN_BLOCKS (BB * NN * 8 / THREADS)   // 2048: 8 lanes per point
#define PREP_BLOCKS 2048
#define PREP_THREADS 256                      // 524288 threads = 1 unit each

__device__ __forceinline__ uint pk_bf16(float a, float b) {
    uint ua = __float_as_uint(a);
    ua = (ua + 0x7fffu + ((ua >> 16) & 1u)) >> 16;
    uint ub = __float_as_uint(b);
    ub = (ub + 0x7fffu + ((ub >> 16) & 1u)) & 0xffff0000u;
    return ua | ub;
}

// x fp32 [16][4096][64] -> bf16 packed uint4 units; unit u = floats 8u..8u+7
// (stays within one row since 8 | 64). xb[u] = row u/8, channel-slot u%8.
__global__ __launch_bounds__(PREP_THREADS)
void prep_kernel(const float4* __restrict__ x4, uint4* __restrict__ xb) {
    const int u = blockIdx.x * PREP_THREADS + threadIdx.x;   // 0..524287
    const float4 v0 = x4[2 * (size_t)u];
    const float4 v1 = x4[2 * (size_t)u + 1];
    xb[u] = make_uint4(pk_bf16(v0.x, v0.y), pk_bf16(v0.z, v0.w),
                       pk_bf16(v1.x, v1.y), pk_bf16(v1.z, v1.w));
}

__global__ __launch_bounds__(THREADS)
void gapool_gather(const uint4* __restrict__ xb,
                   const int* __restrict__ idx32,
                   float* __restrict__ out) {
    const int bid = blockIdx.x;
    const int b = bid & 15;              // bid%8 -> XCD affinity for batch b
    const int seg = bid >> 4;            // 0..127
    const int tid = threadIdx.x;
    const int cl = tid & 7;              // channel slot (8 bf16 = 1 uint4)
    const int p = seg * (THREADS / 8) + (tid >> 3);   // point 0..4095
    const float s = 1.0f / KK;

    // idx dtype probe: int64 with values <4096 -> all odd dwords zero.
    int vprobe = idx32[2 * (tid & 63) + 1];
    const bool is64 = (__ballot(vprobe != 0) == 0ULL);

    const size_t prow = (size_t)b * NN + p;

    // Preload this point's 32 indices across its 8 lanes (4 per lane):
    // lane cl owns neighbors cl*4 .. cl*4+3. Coalesced: 256B (int64) or
    // 128B (int32) contiguous per 8-lane group.
    uint pre0, pre1, pre2, pre3;
    if (is64) {
        const uint4* ip = (const uint4*)idx32 + prow * (KK * 2 / 4) + cl * 2;
        const uint4 A = ip[0], B = ip[1];        // 4 int64; low dwords .x/.z
        pre0 = A.x; pre1 = A.z; pre2 = B.x; pre3 = B.z;
    } else {
        const uint4 A = ((const uint4*)idx32)[prow * (KK / 4) + cl];
        pre0 = A.x; pre1 = A.y; pre2 = A.z; pre3 = A.w;
    }

    const uint4* __restrict__ xbb = xb + (size_t)b * NN * (CC / 8);

    float a[8] = {0.f, 0.f, 0.f, 0.f, 0.f, 0.f, 0.f, 0.f};
#pragma unroll
    for (int t = 0; t < KK; ++t) {
        // neighbor t lives in lane (t>>2) of the group, slot (t&3).
        const uint pj = (t & 3) == 0 ? pre0 : (t & 3) == 1 ? pre1
                      : (t & 3) == 2 ? pre2 : pre3;
        const uint nb = __shfl(pj, t >> 2, 8);
        const uint4 r = xbb[(size_t)nb * (CC / 8) + cl];   // 16B of 128B row
        a[0] += __uint_as_float(r.x << 16);
        a[1] += __uint_as_float(r.x & 0xffff0000u);
        a[2] += __uint_as_float(r.y << 16);
        a[3] += __uint_as_float(r.y & 0xffff0000u);
        a[4] += __uint_as_float(r.z << 16);
        a[5] += __uint_as_float(r.z & 0xffff0000u);
        a[6] += __uint_as_float(r.w << 16);
        a[7] += __uint_as_float(r.w & 0xffff0000u);
    }

    float4* op = (float4*)(out + prow * CC + cl * 8);
    op[0] = make_float4(a[0] * s, a[1] * s, a[2] * s, a[3] * s);
    op[1] = make_float4(a[4] * s, a[5] * s, a[6] * s, a[7] * s);
}

extern "C" void kernel_launch(void* const* d_in, const int* in_sizes, int n_in,
                              void* d_out, int out_size, void* d_ws, size_t ws_size,
                              hipStream_t stream) {
    const float* x     = (const float*)d_in[0];
    const int*   idx32 = (const int*)d_in[1];
    float*       out   = (float*)d_out;
    uint4*       xb    = (uint4*)d_ws;               // 8 MiB bf16 copy of x

    prep_kernel<<<PREP_BLOCKS, PREP_THREADS, 0, stream>>>((const float4*)x, xb);

    gapool_gather<<<MAIN_BLOCKS, THREADS, 0, stream>>>(xb, idx32, out);
}